// Round 8
// baseline (323.242 us; speedup 1.0000x reference)
//
#include <hip/hip_runtime.h>
#include <math.h>

#define IN_NUM 1152
#define IN_DIM 8
#define OUT_NUM 10
#define OUT_DIM 16
#define BATCH 256
#define KTOT 9216            // IN_DIM * IN_NUM; k = d*IN_NUM + i
#define WJ 147456            // 16 * 9216, per-j Wo stride
#define GRID 512

typedef __attribute__((ext_vector_type(8))) short short8;
typedef __attribute__((ext_vector_type(4))) short short4v;
typedef __attribute__((ext_vector_type(4))) float f32x4;
typedef __attribute__((ext_vector_type(4))) unsigned int u32x4;

__device__ __forceinline__ unsigned short f2bf(float f) {
    unsigned int u = __builtin_bit_cast(unsigned int, f);
    u += 0x7FFF + ((u >> 16) & 1);          // RNE
    return (unsigned short)(u >> 16);
}
__device__ __forceinline__ float bf2f(unsigned short h) {
    unsigned int u = ((unsigned int)h) << 16;
    return __builtin_bit_cast(float, u);
}
__device__ __forceinline__ unsigned int cvt_pk_bf16(float lo, float hi) {
    unsigned int r;
    asm("v_cvt_pk_bf16_f32 %0, %1, %2" : "=v"(r) : "v"(lo), "v"(hi));
    return r;
}
// multiply 8 packed bf16 by 8 f32 from LDS, repack (RNE)
__device__ __forceinline__ short8 frag_scale(short8 a, const float* __restrict__ cp) {
    u32x4 u = __builtin_bit_cast(u32x4, a);
    float4 c0 = *reinterpret_cast<const float4*>(cp);
    float4 c1 = *reinterpret_cast<const float4*>(cp + 4);
    u32x4 r;
    r[0] = cvt_pk_bf16(__builtin_bit_cast(float, u[0] << 16) * c0.x,
                       __builtin_bit_cast(float, u[0] & 0xFFFF0000u) * c0.y);
    r[1] = cvt_pk_bf16(__builtin_bit_cast(float, u[1] << 16) * c0.z,
                       __builtin_bit_cast(float, u[1] & 0xFFFF0000u) * c0.w);
    r[2] = cvt_pk_bf16(__builtin_bit_cast(float, u[2] << 16) * c1.x,
                       __builtin_bit_cast(float, u[2] & 0xFFFF0000u) * c1.y);
    r[3] = cvt_pk_bf16(__builtin_bit_cast(float, u[3] << 16) * c1.z,
                       __builtin_bit_cast(float, u[3] & 0xFFFF0000u) * c1.w);
    return __builtin_bit_cast(short8, r);
}

// Device-scope write-through stores (sc1): land at coherence point, no L2
// allocate. Cross-phase buffers are write-once-then-read -> cached consumer
// reads can never be stale.
__device__ __forceinline__ void st_dev_u32(unsigned int* p, unsigned int v) {
    __hip_atomic_store(p, v, __ATOMIC_RELAXED, __HIP_MEMORY_SCOPE_AGENT);
}
__device__ __forceinline__ void st_dev_f32(float* p, float v) {
    __hip_atomic_store(p, v, __ATOMIC_RELAXED, __HIP_MEMORY_SCOPE_AGENT);
}

// ---- two-level grid barrier: all-RELAXED (no buffer_inv/wbl2 anywhere).
// vmcnt(0) drain ensures sc1 stores reached the coherence point first.
__device__ __forceinline__ void gbar(unsigned int* bar, unsigned int epoch) {
    asm volatile("s_waitcnt vmcnt(0)" ::: "memory");
    __syncthreads();
    if (threadIdx.x == 0) {
        const int l = blockIdx.x & 15;
        unsigned int old = __hip_atomic_fetch_add(&bar[l * 32], 1u,
                               __ATOMIC_RELAXED, __HIP_MEMORY_SCOPE_AGENT);
        if ((old & 31u) == 31u) {            // 32nd arrival at this leaf
            unsigned int r = __hip_atomic_fetch_add(&bar[512], 1u,
                               __ATOMIC_RELAXED, __HIP_MEMORY_SCOPE_AGENT);
            if ((r & 15u) == 15u)            // 16th leaf -> release
                __hip_atomic_fetch_add(&bar[544], 1u,
                               __ATOMIC_RELAXED, __HIP_MEMORY_SCOPE_AGENT);
        }
        while (__hip_atomic_load(&bar[544], __ATOMIC_RELAXED,
                                 __HIP_MEMORY_SCOPE_AGENT) < epoch)
            __builtin_amdgcn_s_sleep(4);
    }
    __syncthreads();
}

// ---- phase S: fused [softmax from bp] + [GEMM-s with on-the-fly c] + [squash].
// XCD-grouped: all 16 btiles of j on XCD (j&7). j<8: m=0..15 on xcd j;
// j=8,9: m=16..31 on xcd j-8. Per-XCD A-traffic: 1-2 Wo panels.
__device__ __forceinline__ void phase_S(const unsigned short* __restrict__ Wo,
                                        const unsigned short* __restrict__ xb,
                                        const float* __restrict__ bpa,
                                        const float* __restrict__ bpb,
                                        unsigned short* __restrict__ vb,
                                        float* __restrict__ out,
                                        float scale, int wout, float* LS) {
    const int xcd = blockIdx.x & 7;
    const int m   = blockIdx.x >> 3;         // 0..63
    int j, btile;
    if (m < 16)                 { j = xcd;     btile = m; }
    else if (m < 32 && xcd < 2) { j = xcd + 8; btile = m - 16; }
    else return;
    const int t = threadIdx.x;

    // -- softmax over j' for this block's j: c[j][i] -> LS[0..1151]
    if (bpa) {
        for (int i = t; i < IN_NUM; i += 256) {
            float lg[OUT_NUM];
            float mm = -INFINITY;
            #pragma unroll
            for (int j2 = 0; j2 < OUT_NUM; ++j2) {
                float s = 0.f;
                #pragma unroll
                for (int d = 0; d < IN_DIM; ++d) {
                    s += bpa[(size_t)j2 * KTOT + d * IN_NUM + i];
                    if (bpb) s += bpb[(size_t)j2 * KTOT + d * IN_NUM + i];
                }
                lg[j2] = s * (1.0f / BATCH);
                mm = fmaxf(mm, lg[j2]);
            }
            float den = 0.f, cj = 0.f;
            #pragma unroll
            for (int j2 = 0; j2 < OUT_NUM; ++j2) {
                const float e2 = __expf(lg[j2] - mm);
                den += e2;
                cj += (j2 == j) ? e2 : 0.f;
            }
            LS[i] = cj / den;
        }
        __syncthreads();
    }

    const int w    = t >> 6;
    const int lane = t & 63;
    const int row = lane & 15, kg = lane >> 4;

    const unsigned short* ap = Wo + (size_t)j * WJ + row * KTOT + w * 2304 + kg * 8;
    const unsigned short* bp = xb + (size_t)(btile * 16 + row) * KTOT + w * 2304 + kg * 8;

    f32x4 acc0 = {0.f, 0.f, 0.f, 0.f}, acc1 = {0.f, 0.f, 0.f, 0.f};
    #pragma unroll 4
    for (int it = 0; it < 36; ++it) {        // 36 * 64 = 2304 k per wave
        short8 a0 = *reinterpret_cast<const short8*>(ap);
        short8 b0 = *reinterpret_cast<const short8*>(bp);
        short8 a1 = *reinterpret_cast<const short8*>(ap + 32);
        short8 b1 = *reinterpret_cast<const short8*>(bp + 32);
        if (bpa) {                           // wave-uniform branch
            // i(k) = k % 1152; w*2304 % 1152 == 0 -> i0 = (it*64)%1152
            const int i0 = (it * 64) % IN_NUM;
            const float* cp0 = LS + i0 + kg * 8;
            a0 = frag_scale(a0, cp0);
            a1 = frag_scale(a1, cp0 + 32);   // i0+32+kg*8+7 <= 1151, no wrap
        }
        acc0 = __builtin_amdgcn_mfma_f32_16x16x32_bf16(a0, b0, acc0, 0, 0, 0);
        acc1 = __builtin_amdgcn_mfma_f32_16x16x32_bf16(a1, b1, acc1, 0, 0, 0);
        ap += 64; bp += 64;
    }
    f32x4 acc = acc0 + acc1;
    // D: col(lane&15) -> b, row kg*4+r -> o.  Sred at LS+1152, f at LS+2176
    float* Sred = LS + 1152;
    #pragma unroll
    for (int r = 0; r < 4; ++r) Sred[w * 256 + (kg * 4 + r) * 16 + row] = acc[r];
    __syncthreads();

    const int o = t >> 4, b = t & 15;
    float sum = Sred[0 * 256 + o * 16 + b] + Sred[1 * 256 + o * 16 + b]
              + Sred[2 * 256 + o * 16 + b] + Sred[3 * 256 + o * 16 + b];
    __syncthreads();
    Sred[o * 16 + b] = sum;                  // own slot
    __syncthreads();
    if (t < 16) {                            // b = t: squash factor
        float m2r = 0.f;
        #pragma unroll
        for (int oo = 0; oo < 16; ++oo) { const float q = Sred[oo * 16 + t]; m2r += q * q; }
        const float m2 = m2r * scale * scale;
        Sred[1024 + t] = sqrtf(m2) / (1.0f + m2);
    }
    __syncthreads();
    if (wout) {
        const int b2 = t >> 4, o2 = t & 15;
        out[((size_t)j * BATCH + btile * 16 + b2) * OUT_DIM + o2] =
            Sred[o2 * 16 + b2] * scale * Sred[1024 + b2];   // coalesced f32
    } else if (t < 128) {                    // pack 2 bf16 -> one sc1 u32
        const int oo = t >> 3, b0p = (t & 7) * 2;
        const unsigned int lo = f2bf(Sred[oo * 16 + b0p]     * scale * Sred[1024 + b0p]);
        const unsigned int hi = f2bf(Sred[oo * 16 + b0p + 1] * scale * Sred[1024 + b0p + 1]);
        st_dev_u32((unsigned int*)(vb + (size_t)j * OUT_DIM * BATCH + oo * BATCH
                                   + btile * 16 + b0p), lo | (hi << 16));
    }
}

// ---- phase G: GEMM-G + b-partials, XCD-grouped by kt (kt = xcd + 8*g).
// Per-XCD: 72 kt x 10 j = 720 waves over 256 wave slots -> 3 passes.
__device__ __forceinline__ void phase_G(const unsigned short* __restrict__ xT,
                                        const unsigned short* __restrict__ vb,
                                        const unsigned short* __restrict__ Wo,
                                        float* __restrict__ bpd) {
    const int xcd = blockIdx.x & 7;
    const int m   = blockIdx.x >> 3;         // 0..63
    const int w    = threadIdx.x >> 6;
    const int lane = threadIdx.x & 63;
    const int rc = lane & 15, kg = lane >> 4;
    #pragma unroll 1
    for (int pass = 0; pass < 3; ++pass) {
        const int wv = pass * 256 + m * 4 + w;   // 0..767
        if (wv >= 720) break;
        const int g = wv / 10, j = wv % 10;
        const int kt = xcd + 8 * g;              // < 576

        const unsigned short* ap = xT + (size_t)(kt * 16 + rc) * BATCH + kg * 8;
        const unsigned short* vp = vb + (size_t)j * OUT_DIM * BATCH + rc * BATCH + kg * 8;

        f32x4 acc0 = {0.f, 0.f, 0.f, 0.f}, acc1 = {0.f, 0.f, 0.f, 0.f};
        #pragma unroll
        for (int bb = 0; bb < 4; ++bb) {     // 4 * 64 = 256 = BATCH
            short8 a0 = *reinterpret_cast<const short8*>(ap + bb * 64);
            short8 b0 = *reinterpret_cast<const short8*>(vp + bb * 64);
            acc0 = __builtin_amdgcn_mfma_f32_16x16x32_bf16(a0, b0, acc0, 0, 0, 0);
            short8 a1 = *reinterpret_cast<const short8*>(ap + bb * 64 + 32);
            short8 b1 = *reinterpret_cast<const short8*>(vp + bb * 64 + 32);
            acc1 = __builtin_amdgcn_mfma_f32_16x16x32_bf16(a1, b1, acc1, 0, 0, 0);
        }
        f32x4 acc = acc0 + acc1;
        // lane(rc,kg) holds G[k = kt*16 + kg*4 + r][o = rc]
        const int kbase = kt * 16 + kg * 4;
        short4v w4 = *reinterpret_cast<const short4v*>(
            Wo + (size_t)j * WJ + rc * KTOT + kbase);
        float p[4];
        #pragma unroll
        for (int r = 0; r < 4; ++r) p[r] = acc[r] * bf2f((unsigned short)w4[r]);
        #pragma unroll
        for (int mm = 1; mm < 16; mm <<= 1) {
            #pragma unroll
            for (int r = 0; r < 4; ++r) p[r] += __shfl_xor(p[r], mm);
        }
        if (rc == 0) {
            #pragma unroll
            for (int r = 0; r < 4; ++r)
                st_dev_f32(bpd + (size_t)j * KTOT + kbase + r, p[r]);
        }
    }
}

// ---------------------------------------------------------------------------
__global__ __launch_bounds__(256, 2) void k_all(const float* __restrict__ W,
                                                const float* __restrict__ x,
                                                float* __restrict__ out,
                                                unsigned short* __restrict__ Wo,
                                                unsigned short* __restrict__ xb,
                                                unsigned short* __restrict__ xT,
                                                unsigned short* __restrict__ vb0,
                                                unsigned short* __restrict__ vb1,
                                                float* __restrict__ bp0,
                                                float* __restrict__ bp1,
                                                unsigned int* bar) {
    __shared__ float LS[8320];               // 33.3 KB, unioned across phases
    const int t = threadIdx.x;

    // ---- P: prep. units [0,180): W -> Wo bf16; [180,756): x -> xb, xT bf16.
    for (int unit = blockIdx.x; unit < 756; unit += GRID) {
        if (unit < 180) {
            const int j  = unit / 18;
            const int i0 = (unit % 18) * 64;
            #pragma unroll 4
            for (int st = 0; st < 32; ++st) {
                const int il = st * 2 + (t >> 7);
                const int od = t & 127;
                LS[il * 130 + od] = W[(size_t)(i0 + il) * 1280 + j * 128 + od];
            }
            __syncthreads();
            #pragma unroll 4
            for (int q = 0; q < 16; ++q) {   // 4096 u32 = 128 od x 32 il-pairs
                const int u   = q * 256 + t;
                const int od  = u >> 5;
                const int ilp = (u & 31) * 2;
                const int o = od >> 3, d = od & 7;
                const unsigned int lo = f2bf(LS[ilp * 130 + od]);
                const unsigned int hi = f2bf(LS[(ilp + 1) * 130 + od]);
                st_dev_u32((unsigned int*)(Wo + (size_t)j * WJ + o * KTOT
                                           + d * IN_NUM + i0 + ilp), lo | (hi << 16));
            }
        } else {
            const int bx = unit - 180;
            const int k0 = (bx >> 2) * 64;
            const int b0 = (bx & 3) * 64;
            #pragma unroll 4
            for (int st = 0; st < 16; ++st) {
                const int bl = st * 4 + (t >> 6);
                const int kl = t & 63;
                LS[kl * 65 + bl] = x[(size_t)(b0 + bl) * KTOT + k0 + kl];  // coalesced
            }
            __syncthreads();
            #pragma unroll 4
            for (int q = 0; q < 8; ++q) {    // xb: 2048 u32
                const int u   = q * 256 + t;
                const int bl  = u >> 5;
                const int klp = (u & 31) * 2;
                const unsigned int lo = f2bf(LS[klp * 65 + bl]);
                const unsigned int hi = f2bf(LS[(klp + 1) * 65 + bl]);
                st_dev_u32((unsigned int*)(xb + (size_t)(b0 + bl) * KTOT + k0 + klp),
                           lo | (hi << 16));
            }
            #pragma unroll 4
            for (int q = 0; q < 8; ++q) {    // xT: 2048 u32
                const int u   = q * 256 + t;
                const int kl  = u >> 5;
                const int blp = (u & 31) * 2;
                const unsigned int lo = f2bf(LS[kl * 65 + blp]);
                const unsigned int hi = f2bf(LS[kl * 65 + blp + 1]);
                st_dev_u32((unsigned int*)(xT + (size_t)(k0 + kl) * BATCH + b0 + blp),
                           lo | (hi << 16));
            }
        }
        __syncthreads();
    }
    gbar(bar, 1);
    // iter 0: c uniform 0.1 folded into squash scale (no softmax)
    phase_S(Wo, xb, nullptr, nullptr, vb0, out, 0.1f, 0, LS);
    gbar(bar, 2);
    phase_G(xT, vb0, Wo, bp0);
    gbar(bar, 3);
    // iter 1: softmax(bp0) folded into S
    phase_S(Wo, xb, bp0, nullptr, vb1, out, 1.0f, 0, LS);
    gbar(bar, 4);
    phase_G(xT, vb1, Wo, bp1);
    gbar(bar, 5);
    // iter 2 (final): softmax(bp0+bp1), writes d_out
    phase_S(Wo, xb, bp0, bp1, nullptr, out, 1.0f, 1, LS);
}

// ---------------------------------------------------------------------------
extern "C" void kernel_launch(void* const* d_in, const int* in_sizes, int n_in,
                              void* d_out, int out_size, void* d_ws, size_t ws_size,
                              hipStream_t stream) {
    const float* x = (const float*)d_in[0];   // [256][8][1152]
    const float* W = (const float*)d_in[1];   // [1152][10][16][8]
    float* out = (float*)d_out;               // [10][256][16]
    float* ws = (float*)d_ws;

    unsigned int*   bar = (unsigned int*)ws;                   // 576 u32
    float*          bp0 = ws + 576;                            // 92160 f32
    float*          bp1 = ws + 92736;                          // 92160 f32
    unsigned short* vb0 = (unsigned short*)(ws + 184896);      // 40960 bf16
    unsigned short* vb1 = (unsigned short*)(ws + 205376);      // 40960 bf16
    unsigned short* Wo  = (unsigned short*)(ws + 225856);      // 1474560 bf16
    unsigned short* xb  = (unsigned short*)(ws + 963136);      // 2359296 bf16
    unsigned short* xT  = (unsigned short*)(ws + 2142784);     // 2359296 bf16
    // end: 3322432 f32 = 13.3 MB

    hipMemsetAsync(bar, 0, 576 * sizeof(unsigned int), stream);

    void* args[] = {(void*)&W, (void*)&x, (void*)&out, (void*)&Wo,
                    (void*)&xb, (void*)&xT, (void*)&vb0, (void*)&vb1,
                    (void*)&bp0, (void*)&bp1, (void*)&bar};
    hipLaunchCooperativeKernel((const void*)k_all, dim3(GRID), dim3(256),
                               args, 0, stream);
}

// Round 10
// 314.909 us; speedup vs baseline: 1.0265x; 1.0265x over previous
//
#include <hip/hip_runtime.h>
#include <math.h>

#define IN_NUM 1152
#define IN_DIM 8
#define OUT_NUM 10
#define OUT_DIM 16
#define BATCH 256
#define KTOT 9216            // IN_DIM * IN_NUM; k = d*IN_NUM + i
#define WJ 147456            // 16 * 9216, per-j Wo stride
#define GRID 512

typedef __attribute__((ext_vector_type(8))) short short8;
typedef __attribute__((ext_vector_type(4))) short short4v;
typedef __attribute__((ext_vector_type(4))) float f32x4;
typedef __attribute__((ext_vector_type(4))) unsigned int u32x4;

__device__ __forceinline__ unsigned short f2bf(float f) {
    unsigned int u = __builtin_bit_cast(unsigned int, f);
    u += 0x7FFF + ((u >> 16) & 1);          // RNE
    return (unsigned short)(u >> 16);
}
__device__ __forceinline__ float bf2f(unsigned short h) {
    unsigned int u = ((unsigned int)h) << 16;
    return __builtin_bit_cast(float, u);
}
__device__ __forceinline__ unsigned int cvt_pk_bf16(float lo, float hi) {
    unsigned int r;
    asm("v_cvt_pk_bf16_f32 %0, %1, %2" : "=v"(r) : "v"(lo), "v"(hi));
    return r;
}
// multiply 8 packed bf16 by 8 f32 from LDS, repack (RNE pairs)
__device__ __forceinline__ short8 frag_scale(short8 a, const float* __restrict__ cp) {
    u32x4 u = __builtin_bit_cast(u32x4, a);
    float4 c0 = *reinterpret_cast<const float4*>(cp);
    float4 c1 = *reinterpret_cast<const float4*>(cp + 4);
    u32x4 r;
    r[0] = cvt_pk_bf16(__builtin_bit_cast(float, u[0] << 16) * c0.x,
                       __builtin_bit_cast(float, u[0] & 0xFFFF0000u) * c0.y);
    r[1] = cvt_pk_bf16(__builtin_bit_cast(float, u[1] << 16) * c0.z,
                       __builtin_bit_cast(float, u[1] & 0xFFFF0000u) * c0.w);
    r[2] = cvt_pk_bf16(__builtin_bit_cast(float, u[2] << 16) * c1.x,
                       __builtin_bit_cast(float, u[2] & 0xFFFF0000u) * c1.y);
    r[3] = cvt_pk_bf16(__builtin_bit_cast(float, u[3] << 16) * c1.z,
                       __builtin_bit_cast(float, u[3] & 0xFFFF0000u) * c1.w);
    return __builtin_bit_cast(short8, r);
}

// Device-scope write-through stores (sc1): land at coherence point, no L2
// allocate. Every cross-phase buffer is (a) written exactly once per launch
// before any read and (b) bit-identical across replays (pure MFMA determinism,
// NO atomics) -> cached consumer reads can never observe wrong data, even
// from replay-stale L2 lines.
__device__ __forceinline__ void st_dev_u32(unsigned int* p, unsigned int v) {
    __hip_atomic_store(p, v, __ATOMIC_RELAXED, __HIP_MEMORY_SCOPE_AGENT);
}
__device__ __forceinline__ void st_dev_f32(float* p, float v) {
    __hip_atomic_store(p, v, __ATOMIC_RELAXED, __HIP_MEMORY_SCOPE_AGENT);
}

// ---- two-level grid barrier: all-RELAXED (no buffer_inv/wbl2 anywhere).
// vmcnt(0) drain ensures sc1 stores reached the coherence point first.
__device__ __forceinline__ void gbar(unsigned int* bar, unsigned int epoch) {
    asm volatile("s_waitcnt vmcnt(0)" ::: "memory");
    __syncthreads();
    if (threadIdx.x == 0) {
        const int l = blockIdx.x & 15;
        unsigned int old = __hip_atomic_fetch_add(&bar[l * 32], 1u,
                               __ATOMIC_RELAXED, __HIP_MEMORY_SCOPE_AGENT);
        if ((old & 31u) == 31u) {            // 32nd arrival at this leaf
            unsigned int r = __hip_atomic_fetch_add(&bar[512], 1u,
                               __ATOMIC_RELAXED, __HIP_MEMORY_SCOPE_AGENT);
            if ((r & 15u) == 15u)            // 16th leaf -> release
                __hip_atomic_fetch_add(&bar[544], 1u,
                               __ATOMIC_RELAXED, __HIP_MEMORY_SCOPE_AGENT);
        }
        while (__hip_atomic_load(&bar[544], __ATOMIC_RELAXED,
                                 __HIP_MEMORY_SCOPE_AGENT) < epoch)
            __builtin_amdgcn_s_sleep(4);
    }
    __syncthreads();
}

// ---- phase S: [softmax from bp partials] + [GEMM-s, c folded in-register] +
// [squash]. 2D XCD tiling: xcd=blk&7 owns j in {jg*5..+4} x btile {bg*4..+3}
// (jg=xcd&1, bg=xcd>>1): Wo 1.44MB + xb 1.18MB + bp 0.74MB < 4MB L2,
// resident across ALL iterations. bp read is XCD-shared (20 blocks hit L2).
__device__ __forceinline__ void phase_S(const unsigned short* __restrict__ Wo,
                                        const unsigned short* __restrict__ xb,
                                        const float* __restrict__ bpa,
                                        const float* __restrict__ bpb,
                                        unsigned short* __restrict__ vb,
                                        float* __restrict__ out,
                                        float scale, int wout, float* LS) {
    const int xcd = blockIdx.x & 7;
    const int m   = blockIdx.x >> 3;
    if (m >= 20) return;
    const int jg = xcd & 1, bg = xcd >> 1;
    const int j     = jg * 5 + (m >> 2);
    const int btile = bg * 4 + (m & 3);
    const int t = threadIdx.x;

    // -- softmax for this block's j from bp partials (L2-hot, XCD-shared)
    if (bpa) {
        for (int i = t; i < IN_NUM; i += 256) {
            float lg[OUT_NUM];
            float mm = -INFINITY;
            #pragma unroll
            for (int j2 = 0; j2 < OUT_NUM; ++j2) {
                float s = 0.f;
                #pragma unroll
                for (int d = 0; d < IN_DIM; ++d) {
                    s += bpa[(size_t)j2 * KTOT + d * IN_NUM + i];
                    if (bpb) s += bpb[(size_t)j2 * KTOT + d * IN_NUM + i];
                }
                lg[j2] = s * (1.0f / BATCH);
                mm = fmaxf(mm, lg[j2]);
            }
            float den = 0.f, cj = 0.f;
            #pragma unroll
            for (int j2 = 0; j2 < OUT_NUM; ++j2) {
                const float e2 = __expf(lg[j2] - mm);
                den += e2;
                if (j2 == j) cj = e2;
            }
            LS[i] = cj / den;
        }
        __syncthreads();
    }

    const int w    = t >> 6;
    const int lane = t & 63;
    const int row = lane & 15, kg = lane >> 4;

    const unsigned short* ap = Wo + (size_t)j * WJ + row * KTOT + w * 2304 + kg * 8;
    const unsigned short* bp = xb + (size_t)(btile * 16 + row) * KTOT + w * 2304 + kg * 8;

    f32x4 acc0 = {0.f, 0.f, 0.f, 0.f}, acc1 = {0.f, 0.f, 0.f, 0.f};
    #pragma unroll 4
    for (int it = 0; it < 36; ++it) {        // 36 * 64 = 2304 k per wave
        short8 a0 = *reinterpret_cast<const short8*>(ap);
        short8 b0 = *reinterpret_cast<const short8*>(bp);
        short8 a1 = *reinterpret_cast<const short8*>(ap + 32);
        short8 b1 = *reinterpret_cast<const short8*>(bp + 32);
        if (bpa) {                           // wave-uniform branch
            // i(k) = k % 1152; w*2304 % 1152 == 0 -> i0 = (it*64)%1152
            const int i0 = (it * 64) % IN_NUM;
            const float* cp0 = LS + i0 + kg * 8;   // no wrap within the 8-run
            a0 = frag_scale(a0, cp0);
            a1 = frag_scale(a1, cp0 + 32);         // +32: <= 1151, no wrap
        }
        acc0 = __builtin_amdgcn_mfma_f32_16x16x32_bf16(a0, b0, acc0, 0, 0, 0);
        acc1 = __builtin_amdgcn_mfma_f32_16x16x32_bf16(a1, b1, acc1, 0, 0, 0);
        ap += 64; bp += 64;
    }
    f32x4 acc = acc0 + acc1;
    // D: col(lane&15) -> b, row kg*4+r -> o.  Sred at LS+1152
    float* Sred = LS + 1152;
    #pragma unroll
    for (int r = 0; r < 4; ++r) Sred[w * 256 + (kg * 4 + r) * 16 + row] = acc[r];
    __syncthreads();

    const int o = t >> 4, b = t & 15;
    float sum = Sred[0 * 256 + o * 16 + b] + Sred[1 * 256 + o * 16 + b]
              + Sred[2 * 256 + o * 16 + b] + Sred[3 * 256 + o * 16 + b];
    __syncthreads();
    Sred[o * 16 + b] = sum;                  // own slot
    __syncthreads();
    if (t < 16) {                            // b = t: squash factor
        float m2r = 0.f;
        #pragma unroll
        for (int oo = 0; oo < 16; ++oo) { const float q = Sred[oo * 16 + t]; m2r += q * q; }
        const float m2 = m2r * scale * scale;
        Sred[1024 + t] = sqrtf(m2) / (1.0f + m2);
    }
    __syncthreads();
    if (wout) {
        const int b2 = t >> 4, o2 = t & 15;
        out[((size_t)j * BATCH + btile * 16 + b2) * OUT_DIM + o2] =
            Sred[o2 * 16 + b2] * scale * Sred[1024 + b2];   // coalesced f32
    } else if (t < 128) {                    // pack 2 bf16 -> one sc1 u32
        const int oo = t >> 3, b0p = (t & 7) * 2;
        const unsigned int lo = f2bf(Sred[oo * 16 + b0p]     * scale * Sred[1024 + b0p]);
        const unsigned int hi = f2bf(Sred[oo * 16 + b0p + 1] * scale * Sred[1024 + b0p + 1]);
        st_dev_u32((unsigned int*)(vb + (size_t)j * OUT_DIM * BATCH + oo * BATCH
                                   + btile * 16 + b0p), lo | (hi << 16));
    }
}

// ---- phase G: GEMM-G + b-partials via sc1 (write-once, NO atomics).
// kt-grouped per XCD (kt=xcd+8g): xT/Wo stripes ~1.2MB, L2-resident.
__device__ __forceinline__ void phase_G(const unsigned short* __restrict__ xT,
                                        const unsigned short* __restrict__ vb,
                                        const unsigned short* __restrict__ Wo,
                                        float* __restrict__ bpd) {
    const int xcd = blockIdx.x & 7;
    const int m   = blockIdx.x >> 3;         // 0..63
    const int w    = threadIdx.x >> 6;
    const int lane = threadIdx.x & 63;
    const int rc = lane & 15, kg = lane >> 4;
    #pragma unroll 1
    for (int pass = 0; pass < 3; ++pass) {
        const int wv = pass * 256 + m * 4 + w;   // per-XCD unit id, 0..767
        if (wv >= 720) break;                    // 72 g x 10 j
        const int g = wv / 10, j = wv % 10;
        const int kt = xcd + 8 * g;              // < 576

        const unsigned short* ap = xT + (size_t)(kt * 16 + rc) * BATCH + kg * 8;
        const unsigned short* vp = vb + (size_t)j * OUT_DIM * BATCH + rc * BATCH + kg * 8;

        f32x4 acc0 = {0.f, 0.f, 0.f, 0.f}, acc1 = {0.f, 0.f, 0.f, 0.f};
        #pragma unroll
        for (int bb = 0; bb < 4; ++bb) {     // 4 * 64 = 256 = BATCH
            short8 a0 = *reinterpret_cast<const short8*>(ap + bb * 64);
            short8 b0 = *reinterpret_cast<const short8*>(vp + bb * 64);
            acc0 = __builtin_amdgcn_mfma_f32_16x16x32_bf16(a0, b0, acc0, 0, 0, 0);
            short8 a1 = *reinterpret_cast<const short8*>(ap + bb * 64 + 32);
            short8 b1 = *reinterpret_cast<const short8*>(vp + bb * 64 + 32);
            acc1 = __builtin_amdgcn_mfma_f32_16x16x32_bf16(a1, b1, acc1, 0, 0, 0);
        }
        f32x4 acc = acc0 + acc1;
        // lane(rc,kg) holds G[k = kt*16 + kg*4 + r][o = rc]
        const int kbase = kt * 16 + kg * 4;
        short4v w4 = *reinterpret_cast<const short4v*>(
            Wo + (size_t)j * WJ + rc * KTOT + kbase);
        float p[4];
        #pragma unroll
        for (int r = 0; r < 4; ++r) p[r] = acc[r] * bf2f((unsigned short)w4[r]);
        #pragma unroll
        for (int mm = 1; mm < 16; mm <<= 1) {
            #pragma unroll
            for (int r = 0; r < 4; ++r) p[r] += __shfl_xor(p[r], mm);
        }
        if (rc == 0) {
            #pragma unroll
            for (int r = 0; r < 4; ++r)
                st_dev_f32(bpd + (size_t)j * KTOT + kbase + r, p[r]);
        }
    }
}

// ---------------------------------------------------------------------------
__global__ __launch_bounds__(256, 2) void k_all(const float* __restrict__ W,
                                                const float* __restrict__ x,
                                                float* __restrict__ out,
                                                unsigned short* __restrict__ Wo,
                                                unsigned short* __restrict__ xb,
                                                unsigned short* __restrict__ xT,
                                                unsigned short* __restrict__ vb0,
                                                unsigned short* __restrict__ vb1,
                                                float* __restrict__ bp0,
                                                float* __restrict__ bp1,
                                                unsigned int* bar) {
    __shared__ float LS[8320];               // 33.3 KB, unioned across phases
    const int t = threadIdx.x;

    // ---- P: prep. units [0,180): W -> Wo bf16; [180,756): x -> xb, xT bf16.
    for (int unit = blockIdx.x; unit < 756; unit += GRID) {
        if (unit < 180) {
            const int j  = unit / 18;
            const int i0 = (unit % 18) * 64;
            #pragma unroll 4
            for (int st = 0; st < 32; ++st) {
                const int il = st * 2 + (t >> 7);
                const int od = t & 127;
                LS[il * 130 + od] = W[(size_t)(i0 + il) * 1280 + j * 128 + od];
            }
            __syncthreads();
            #pragma unroll 4
            for (int q = 0; q < 16; ++q) {   // 4096 u32 = 128 od x 32 il-pairs
                const int u   = q * 256 + t;
                const int od  = u >> 5;
                const int ilp = (u & 31) * 2;
                const int o = od >> 3, d = od & 7;
                const unsigned int lo = f2bf(LS[ilp * 130 + od]);
                const unsigned int hi = f2bf(LS[(ilp + 1) * 130 + od]);
                st_dev_u32((unsigned int*)(Wo + (size_t)j * WJ + o * KTOT
                                           + d * IN_NUM + i0 + ilp), lo | (hi << 16));
            }
        } else {
            const int bx = unit - 180;
            const int k0 = (bx >> 2) * 64;
            const int b0 = (bx & 3) * 64;
            #pragma unroll 4
            for (int st = 0; st < 16; ++st) {
                const int bl = st * 4 + (t >> 6);
                const int kl = t & 63;
                LS[kl * 65 + bl] = x[(size_t)(b0 + bl) * KTOT + k0 + kl];  // coalesced
            }
            __syncthreads();
            #pragma unroll 4
            for (int q = 0; q < 8; ++q) {    // xb: 2048 u32
                const int u   = q * 256 + t;
                const int bl  = u >> 5;
                const int klp = (u & 31) * 2;
                const unsigned int lo = f2bf(LS[klp * 65 + bl]);
                const unsigned int hi = f2bf(LS[(klp + 1) * 65 + bl]);
                st_dev_u32((unsigned int*)(xb + (size_t)(b0 + bl) * KTOT + k0 + klp),
                           lo | (hi << 16));
            }
            #pragma unroll 4
            for (int q = 0; q < 8; ++q) {    // xT: 2048 u32
                const int u   = q * 256 + t;
                const int kl  = u >> 5;
                const int blp = (u & 31) * 2;
                const unsigned int lo = f2bf(LS[kl * 65 + blp]);
                const unsigned int hi = f2bf(LS[kl * 65 + blp + 1]);
                st_dev_u32((unsigned int*)(xT + (size_t)(k0 + kl) * BATCH + b0 + blp),
                           lo | (hi << 16));
            }
        }
        __syncthreads();
    }
    gbar(bar, 1);
    // iter 0: c uniform 0.1 folded into squash scale (no softmax)
    phase_S(Wo, xb, nullptr, nullptr, vb0, out, 0.1f, 0, LS);
    gbar(bar, 2);
    phase_G(xT, vb0, Wo, bp0);
    gbar(bar, 3);
    // iter 1: softmax(bp0) folded into S
    phase_S(Wo, xb, bp0, nullptr, vb1, out, 1.0f, 0, LS);
    gbar(bar, 4);
    phase_G(xT, vb1, Wo, bp1);
    gbar(bar, 5);
    // iter 2 (final): softmax(bp0+bp1), writes d_out
    phase_S(Wo, xb, bp0, bp1, nullptr, out, 1.0f, 1, LS);
}

// ---------------------------------------------------------------------------
extern "C" void kernel_launch(void* const* d_in, const int* in_sizes, int n_in,
                              void* d_out, int out_size, void* d_ws, size_t ws_size,
                              hipStream_t stream) {
    const float* x = (const float*)d_in[0];   // [256][8][1152]
    const float* W = (const float*)d_in[1];   // [1152][10][16][8]
    float* out = (float*)d_out;               // [10][256][16]
    float* ws = (float*)d_ws;

    unsigned int*   bar = (unsigned int*)ws;                   // 576 u32
    float*          bp0 = ws + 576;                            // 92160 f32
    float*          bp1 = ws + 92736;                          // 92160 f32
    unsigned short* vb0 = (unsigned short*)(ws + 184896);      // 40960 bf16
    unsigned short* vb1 = (unsigned short*)(ws + 205376);      // 40960 bf16
    unsigned short* Wo  = (unsigned short*)(ws + 225856);      // 1474560 bf16
    unsigned short* xb  = (unsigned short*)(ws + 963136);      // 2359296 bf16
    unsigned short* xT  = (unsigned short*)(ws + 2142784);     // 2359296 bf16
    // end: 3322432 f32 = 13.3 MB

    hipMemsetAsync(bar, 0, 576 * sizeof(unsigned int), stream);

    void* args[] = {(void*)&W, (void*)&x, (void*)&out, (void*)&Wo,
                    (void*)&xb, (void*)&xT, (void*)&vb0, (void*)&vb1,
                    (void*)&bp0, (void*)&bp1, (void*)&bar};
    hipLaunchCooperativeKernel((const void*)k_all, dim3(GRID), dim3(256),
                               args, 0, stream);
}

// Round 11
// 172.913 us; speedup vs baseline: 1.8694x; 1.8212x over previous
//
#include <hip/hip_runtime.h>
#include <math.h>

#define IN_NUM 1152
#define IN_DIM 8
#define OUT_NUM 10
#define OUT_DIM 16
#define BATCH 256
#define KTOT 9216            // IN_DIM * IN_NUM; k = d*IN_NUM + i
#define WJ 147456            // 16 * 9216, per-j Wo stride
#define GRID 512

typedef __attribute__((ext_vector_type(8))) short short8;
typedef __attribute__((ext_vector_type(4))) short short4v;
typedef __attribute__((ext_vector_type(4))) float f32x4;
typedef __attribute__((ext_vector_type(4))) unsigned int u32x4;

__device__ __forceinline__ unsigned short f2bf(float f) {
    unsigned int u = __builtin_bit_cast(unsigned int, f);
    u += 0x7FFF + ((u >> 16) & 1);          // RNE
    return (unsigned short)(u >> 16);
}
__device__ __forceinline__ float bf2f(unsigned short h) {
    unsigned int u = ((unsigned int)h) << 16;
    return __builtin_bit_cast(float, u);
}
__device__ __forceinline__ unsigned int cvt_pk_bf16(float lo, float hi) {
    unsigned int r;
    asm("v_cvt_pk_bf16_f32 %0, %1, %2" : "=v"(r) : "v"(lo), "v"(hi));
    return r;
}
// multiply 8 packed bf16 by 8 f32 from LDS, repack (RNE pairs)
__device__ __forceinline__ short8 frag_scale(short8 a, const float* __restrict__ cp) {
    u32x4 u = __builtin_bit_cast(u32x4, a);
    float4 c0 = *reinterpret_cast<const float4*>(cp);
    float4 c1 = *reinterpret_cast<const float4*>(cp + 4);
    u32x4 r;
    r[0] = cvt_pk_bf16(__builtin_bit_cast(float, u[0] << 16) * c0.x,
                       __builtin_bit_cast(float, u[0] & 0xFFFF0000u) * c0.y);
    r[1] = cvt_pk_bf16(__builtin_bit_cast(float, u[1] << 16) * c0.z,
                       __builtin_bit_cast(float, u[1] & 0xFFFF0000u) * c0.w);
    r[2] = cvt_pk_bf16(__builtin_bit_cast(float, u[2] << 16) * c1.x,
                       __builtin_bit_cast(float, u[2] & 0xFFFF0000u) * c1.y);
    r[3] = cvt_pk_bf16(__builtin_bit_cast(float, u[3] << 16) * c1.z,
                       __builtin_bit_cast(float, u[3] & 0xFFFF0000u) * c1.w);
    return __builtin_bit_cast(short8, r);
}

// Device-scope write-through stores (sc1): land at coherence point, no L2
// allocate. Every cross-phase buffer is written exactly once per launch before
// any read AND is bit-identical across replays (pure MFMA determinism, no
// atomics on data) -> cached consumer reads can never observe wrong data.
__device__ __forceinline__ void st_dev_u32(unsigned int* p, unsigned int v) {
    __hip_atomic_store(p, v, __ATOMIC_RELAXED, __HIP_MEMORY_SCOPE_AGENT);
}
__device__ __forceinline__ void st_dev_f32(float* p, float v) {
    __hip_atomic_store(p, v, __ATOMIC_RELAXED, __HIP_MEMORY_SCOPE_AGENT);
}

// ---- slot grid barrier: contention-free arrivals (each block OWNS slot[bid],
// plain sc1 store of the epoch -- no RMW serialization). Block 0 polls all 512
// slots (2 per thread) and raises the release flag; others spin relaxed.
// bar[0..511]: slots; bar[544]: release flag (own cache line).
__device__ __forceinline__ void gbar(unsigned int* bar, unsigned int epoch) {
    asm volatile("s_waitcnt vmcnt(0)" ::: "memory");
    __syncthreads();
    const int bid = blockIdx.x;
    if (bid == 0) {
        if (threadIdx.x == 0) st_dev_u32(&bar[0], epoch);
        for (;;) {
            unsigned int s0 = __hip_atomic_load(&bar[threadIdx.x],
                                  __ATOMIC_RELAXED, __HIP_MEMORY_SCOPE_AGENT);
            unsigned int s1 = __hip_atomic_load(&bar[256 + threadIdx.x],
                                  __ATOMIC_RELAXED, __HIP_MEMORY_SCOPE_AGENT);
            const int ok = (s0 >= epoch) && (s1 >= epoch);
            if (__syncthreads_count(ok) == 256) break;
            __builtin_amdgcn_s_sleep(2);
        }
        if (threadIdx.x == 0) st_dev_u32(&bar[544], epoch);
        __syncthreads();
    } else {
        if (threadIdx.x == 0) {
            st_dev_u32(&bar[bid], epoch);
            while (__hip_atomic_load(&bar[544], __ATOMIC_RELAXED,
                                     __HIP_MEMORY_SCOPE_AGENT) < epoch)
                __builtin_amdgcn_s_sleep(4);
        }
        __syncthreads();
    }
}

// ---- phase C: logits + softmax, computed ONCE per (i,j) (kills R10's 160x
// redundant bp reads). 5 blocks, thread = i. Reads bp partials (summed over d),
// writes ct[j][i] f32 via sc1 (46 KB).
__device__ __forceinline__ void phase_C(const float* __restrict__ bpa,
                                        const float* __restrict__ bpb,
                                        float* __restrict__ ct) {
    const int i = blockIdx.x * 256 + threadIdx.x;
    if (blockIdx.x >= 5 || i >= IN_NUM) return;
    float lg[OUT_NUM];
    float mm = -INFINITY;
    #pragma unroll
    for (int j2 = 0; j2 < OUT_NUM; ++j2) {
        float s = 0.f;
        #pragma unroll
        for (int d = 0; d < IN_DIM; ++d) {
            s += bpa[(size_t)j2 * KTOT + d * IN_NUM + i];
            if (bpb) s += bpb[(size_t)j2 * KTOT + d * IN_NUM + i];
        }
        lg[j2] = s * (1.0f / BATCH);
        mm = fmaxf(mm, lg[j2]);
    }
    float den = 0.f;
    #pragma unroll
    for (int j2 = 0; j2 < OUT_NUM; ++j2) { lg[j2] = __expf(lg[j2] - mm); den += lg[j2]; }
    const float inv = 1.0f / den;
    #pragma unroll
    for (int j2 = 0; j2 < OUT_NUM; ++j2)
        st_dev_f32(ct + (size_t)j2 * IN_NUM + i, lg[j2] * inv);   // coalesced over i
}

// ---- phase S: [load ct row] + [GEMM-s, c folded in-register] + [squash].
// 2D XCD tiling: xcd=blk&7 owns j in {jg*5..+4} x btile {bg*4..+3}:
// Wo 1.44MB + xb 1.18MB < 4MB L2, resident across ALL iterations.
__device__ __forceinline__ void phase_S(const unsigned short* __restrict__ Wo,
                                        const unsigned short* __restrict__ xb,
                                        const float* __restrict__ ct,
                                        unsigned short* __restrict__ vb,
                                        float* __restrict__ out,
                                        float scale, int wout, float* LS) {
    const int xcd = blockIdx.x & 7;
    const int m   = blockIdx.x >> 3;
    if (m >= 20) return;
    const int jg = xcd & 1, bg = xcd >> 1;
    const int j     = jg * 5 + (m >> 2);
    const int btile = bg * 4 + (m & 3);
    const int t = threadIdx.x;

    if (ct) {                                // 4.6 KB c-row -> LDS
        for (int i = t; i < IN_NUM; i += 256) LS[i] = ct[(size_t)j * IN_NUM + i];
        __syncthreads();
    }

    const int w    = t >> 6;
    const int lane = t & 63;
    const int row = lane & 15, kg = lane >> 4;

    const unsigned short* ap = Wo + (size_t)j * WJ + row * KTOT + w * 2304 + kg * 8;
    const unsigned short* bp = xb + (size_t)(btile * 16 + row) * KTOT + w * 2304 + kg * 8;

    f32x4 acc0 = {0.f, 0.f, 0.f, 0.f}, acc1 = {0.f, 0.f, 0.f, 0.f};
    #pragma unroll 4
    for (int it = 0; it < 36; ++it) {        // 36 * 64 = 2304 k per wave
        short8 a0 = *reinterpret_cast<const short8*>(ap);
        short8 b0 = *reinterpret_cast<const short8*>(bp);
        short8 a1 = *reinterpret_cast<const short8*>(ap + 32);
        short8 b1 = *reinterpret_cast<const short8*>(bp + 32);
        if (ct) {                            // wave-uniform branch
            // i(k) = k % 1152; w*2304 % 1152 == 0 -> i0 = (it*64)%1152
            const int i0 = (it * 64) % IN_NUM;
            const float* cp0 = LS + i0 + kg * 8;   // no wrap within the 8-run
            a0 = frag_scale(a0, cp0);
            a1 = frag_scale(a1, cp0 + 32);         // +32: <= 1151, no wrap
        }
        acc0 = __builtin_amdgcn_mfma_f32_16x16x32_bf16(a0, b0, acc0, 0, 0, 0);
        acc1 = __builtin_amdgcn_mfma_f32_16x16x32_bf16(a1, b1, acc1, 0, 0, 0);
        ap += 64; bp += 64;
    }
    f32x4 acc = acc0 + acc1;
    // D: col(lane&15) -> b, row kg*4+r -> o.  Sred at LS+1152
    float* Sred = LS + 1152;
    #pragma unroll
    for (int r = 0; r < 4; ++r) Sred[w * 256 + (kg * 4 + r) * 16 + row] = acc[r];
    __syncthreads();

    const int o = t >> 4, b = t & 15;
    float sum = Sred[0 * 256 + o * 16 + b] + Sred[1 * 256 + o * 16 + b]
              + Sred[2 * 256 + o * 16 + b] + Sred[3 * 256 + o * 16 + b];
    __syncthreads();
    Sred[o * 16 + b] = sum;                  // own slot
    __syncthreads();
    if (t < 16) {                            // b = t: squash factor
        float m2r = 0.f;
        #pragma unroll
        for (int oo = 0; oo < 16; ++oo) { const float q = Sred[oo * 16 + t]; m2r += q * q; }
        const float m2 = m2r * scale * scale;
        Sred[1024 + t] = sqrtf(m2) / (1.0f + m2);
    }
    __syncthreads();
    if (wout) {
        const int b2 = t >> 4, o2 = t & 15;
        out[((size_t)j * BATCH + btile * 16 + b2) * OUT_DIM + o2] =
            Sred[o2 * 16 + b2] * scale * Sred[1024 + b2];   // coalesced f32
    } else if (t < 128) {                    // pack 2 bf16 -> one sc1 u32
        const int oo = t >> 3, b0p = (t & 7) * 2;
        const unsigned int lo = f2bf(Sred[oo * 16 + b0p]     * scale * Sred[1024 + b0p]);
        const unsigned int hi = f2bf(Sred[oo * 16 + b0p + 1] * scale * Sred[1024 + b0p + 1]);
        st_dev_u32((unsigned int*)(vb + (size_t)j * OUT_DIM * BATCH + oo * BATCH
                                   + btile * 16 + b0p), lo | (hi << 16));
    }
}

// ---- phase G: GEMM-G + b-partials via sc1 (write-once, NO atomics).
// kt-grouped per XCD (kt=xcd+8g): xT/Wo stripes ~1.2MB, L2-resident.
__device__ __forceinline__ void phase_G(const unsigned short* __restrict__ xT,
                                        const unsigned short* __restrict__ vb,
                                        const unsigned short* __restrict__ Wo,
                                        float* __restrict__ bpd) {
    const int xcd = blockIdx.x & 7;
    const int m   = blockIdx.x >> 3;         // 0..63
    const int w    = threadIdx.x >> 6;
    const int lane = threadIdx.x & 63;
    const int rc = lane & 15, kg = lane >> 4;
    #pragma unroll 1
    for (int pass = 0; pass < 3; ++pass) {
        const int wv = pass * 256 + m * 4 + w;   // per-XCD unit id, 0..767
        if (wv >= 720) break;                    // 72 g x 10 j
        const int g = wv / 10, j = wv % 10;
        const int kt = xcd + 8 * g;              // < 576

        const unsigned short* ap = xT + (size_t)(kt * 16 + rc) * BATCH + kg * 8;
        const unsigned short* vp = vb + (size_t)j * OUT_DIM * BATCH + rc * BATCH + kg * 8;

        f32x4 acc0 = {0.f, 0.f, 0.f, 0.f}, acc1 = {0.f, 0.f, 0.f, 0.f};
        #pragma unroll
        for (int bb = 0; bb < 4; ++bb) {     // 4 * 64 = 256 = BATCH
            short8 a0 = *reinterpret_cast<const short8*>(ap + bb * 64);
            short8 b0 = *reinterpret_cast<const short8*>(vp + bb * 64);
            acc0 = __builtin_amdgcn_mfma_f32_16x16x32_bf16(a0, b0, acc0, 0, 0, 0);
            short8 a1 = *reinterpret_cast<const short8*>(ap + bb * 64 + 32);
            short8 b1 = *reinterpret_cast<const short8*>(vp + bb * 64 + 32);
            acc1 = __builtin_amdgcn_mfma_f32_16x16x32_bf16(a1, b1, acc1, 0, 0, 0);
        }
        f32x4 acc = acc0 + acc1;
        // lane(rc,kg) holds G[k = kt*16 + kg*4 + r][o = rc]
        const int kbase = kt * 16 + kg * 4;
        short4v w4 = *reinterpret_cast<const short4v*>(
            Wo + (size_t)j * WJ + rc * KTOT + kbase);
        float p[4];
        #pragma unroll
        for (int r = 0; r < 4; ++r) p[r] = acc[r] * bf2f((unsigned short)w4[r]);
        #pragma unroll
        for (int mm = 1; mm < 16; mm <<= 1) {
            #pragma unroll
            for (int r = 0; r < 4; ++r) p[r] += __shfl_xor(p[r], mm);
        }
        if (rc == 0) {
            #pragma unroll
            for (int r = 0; r < 4; ++r)
                st_dev_f32(bpd + (size_t)j * KTOT + kbase + r, p[r]);
        }
    }
}

// ---------------------------------------------------------------------------
__global__ __launch_bounds__(256, 2) void k_all(const float* __restrict__ W,
                                                const float* __restrict__ x,
                                                float* __restrict__ out,
                                                unsigned short* __restrict__ Wo,
                                                unsigned short* __restrict__ xb,
                                                unsigned short* __restrict__ xT,
                                                unsigned short* __restrict__ vb0,
                                                unsigned short* __restrict__ vb1,
                                                float* __restrict__ bp0,
                                                float* __restrict__ bp1,
                                                float* __restrict__ ct,
                                                unsigned int* bar) {
    __shared__ float LS[8320];               // 33.3 KB, unioned across phases
    const int t = threadIdx.x;

    // ---- P: prep. units [0,180): W -> Wo bf16; [180,756): x -> xb, xT bf16.
    for (int unit = blockIdx.x; unit < 756; unit += GRID) {
        if (unit < 180) {
            const int j  = unit / 18;
            const int i0 = (unit % 18) * 64;
            #pragma unroll 4
            for (int st = 0; st < 32; ++st) {
                const int il = st * 2 + (t >> 7);
                const int od = t & 127;
                LS[il * 130 + od] = W[(size_t)(i0 + il) * 1280 + j * 128 + od];
            }
            __syncthreads();
            #pragma unroll 4
            for (int q = 0; q < 16; ++q) {   // 4096 u32 = 128 od x 32 il-pairs
                const int u   = q * 256 + t;
                const int od  = u >> 5;
                const int ilp = (u & 31) * 2;
                const int o = od >> 3, d = od & 7;
                const unsigned int lo = f2bf(LS[ilp * 130 + od]);
                const unsigned int hi = f2bf(LS[(ilp + 1) * 130 + od]);
                st_dev_u32((unsigned int*)(Wo + (size_t)j * WJ + o * KTOT
                                           + d * IN_NUM + i0 + ilp), lo | (hi << 16));
            }
        } else {
            const int bx = unit - 180;
            const int k0 = (bx >> 2) * 64;
            const int b0 = (bx & 3) * 64;
            #pragma unroll 4
            for (int st = 0; st < 16; ++st) {
                const int bl = st * 4 + (t >> 6);
                const int kl = t & 63;
                LS[kl * 65 + bl] = x[(size_t)(b0 + bl) * KTOT + k0 + kl];  // coalesced
            }
            __syncthreads();
            #pragma unroll 4
            for (int q = 0; q < 8; ++q) {    // xb: 2048 u32
                const int u   = q * 256 + t;
                const int bl  = u >> 5;
                const int klp = (u & 31) * 2;
                const unsigned int lo = f2bf(LS[klp * 65 + bl]);
                const unsigned int hi = f2bf(LS[(klp + 1) * 65 + bl]);
                st_dev_u32((unsigned int*)(xb + (size_t)(b0 + bl) * KTOT + k0 + klp),
                           lo | (hi << 16));
            }
            #pragma unroll 4
            for (int q = 0; q < 8; ++q) {    // xT: 2048 u32
                const int u   = q * 256 + t;
                const int kl  = u >> 5;
                const int blp = (u & 31) * 2;
                const unsigned int lo = f2bf(LS[kl * 65 + blp]);
                const unsigned int hi = f2bf(LS[kl * 65 + blp + 1]);
                st_dev_u32((unsigned int*)(xT + (size_t)(k0 + kl) * BATCH + b0 + blp),
                           lo | (hi << 16));
            }
        }
        __syncthreads();
    }
    gbar(bar, 1);
    // iter 0: c uniform 0.1 folded into squash scale (no softmax)
    phase_S(Wo, xb, nullptr, vb0, out, 0.1f, 0, LS);
    gbar(bar, 2);
    phase_G(xT, vb0, Wo, bp0);
    gbar(bar, 3);
    // iter 1
    phase_C(bp0, nullptr, ct);
    gbar(bar, 4);
    phase_S(Wo, xb, ct, vb1, out, 1.0f, 0, LS);
    gbar(bar, 5);
    phase_G(xT, vb1, Wo, bp1);
    gbar(bar, 6);
    // iter 2 (final)
    phase_C(bp0, bp1, ct);
    gbar(bar, 7);
    phase_S(Wo, xb, ct, nullptr, out, 1.0f, 1, LS);
}

// ---------------------------------------------------------------------------
extern "C" void kernel_launch(void* const* d_in, const int* in_sizes, int n_in,
                              void* d_out, int out_size, void* d_ws, size_t ws_size,
                              hipStream_t stream) {
    const float* x = (const float*)d_in[0];   // [256][8][1152]
    const float* W = (const float*)d_in[1];   // [1152][10][16][8]
    float* out = (float*)d_out;               // [10][256][16]
    float* ws = (float*)d_ws;

    unsigned int*   bar = (unsigned int*)ws;                   // 576 u32
    float*          ct  = ws + 576;                            // 11520 f32
    float*          bp0 = ws + 12096;                          // 92160 f32
    float*          bp1 = ws + 104256;                         // 92160 f32
    unsigned short* vb0 = (unsigned short*)(ws + 196416);      // 40960 bf16
    unsigned short* vb1 = (unsigned short*)(ws + 216896);      // 40960 bf16
    unsigned short* Wo  = (unsigned short*)(ws + 237376);      // 1474560 bf16
    unsigned short* xb  = (unsigned short*)(ws + 974656);      // 2359296 bf16
    unsigned short* xT  = (unsigned short*)(ws + 2154304);     // 2359296 bf16
    // end: 3333952 f32 = 13.3 MB

    hipMemsetAsync(bar, 0, 576 * sizeof(unsigned int), stream);

    void* args[] = {(void*)&W, (void*)&x, (void*)&out, (void*)&Wo,
                    (void*)&xb, (void*)&xT, (void*)&vb0, (void*)&vb1,
                    (void*)&bp0, (void*)&bp1, (void*)&ct, (void*)&bar};
    hipLaunchCooperativeKernel((const void*)k_all, dim3(GRID), dim3(256),
                               args, 0, stream);
}